// Round 9
// baseline (165.586 us; speedup 1.0000x reference)
//
#include <hip/hip_runtime.h>
#include <hip/hip_bf16.h>

#define DD 256
#define NROWS 16384
#define NBLK 512  // 2 blocks/CU of 512 thr -- all co-resident (barrier-safe)

typedef float f32x4 __attribute__((ext_vector_type(4)));
typedef __bf16 bf16x8 __attribute__((ext_vector_type(8)));

__device__ __forceinline__ void gl2lds16(const void* g, void* l) {
  __builtin_amdgcn_global_load_lds(
      (const __attribute__((address_space(1))) void*)g,
      (__attribute__((address_space(3))) void*)l, 16, 0, 0);
}

__device__ __forceinline__ bf16x8 cvt8(f32x4 lo, f32x4 hi) {
  bf16x8 v;
#pragma unroll
  for (int j = 0; j < 4; ++j) {
    v[j] = (__bf16)lo[j];
    v[4 + j] = (__bf16)hi[j];
  }
  return v;
}

// ---------------------------------------------------------------------------
// ONE launch. Phase 1: Wc = Wout@Wv (bf16) + bc = bout + Wout@bv, all weight
// traffic via global_load_lds DMA. Hand-rolled all-resident grid barrier
// (ctr zeroed per replay by a memset node). Phase 2: out = x + x@Wc^T + bc,
// R7-verified tile: DMA'd XOR-swizzled Wc slice + bf16 x tile + 8 MFMA/wave.
// Block b: Wc row i=b>>1 cols [128(b&1),+128) (phase 1); rows [(b>>1)*64,+64)
// x cols [128(b&1),+128) of out (phase 2, 4 rowtiles of 16).
// ---------------------------------------------------------------------------
__global__ __launch_bounds__(512, 4) void fused_knn(
    const float* __restrict__ x, const float* __restrict__ Wqkv,
    const float* __restrict__ bqkv, const float* __restrict__ Wout,
    const float* __restrict__ bout, __bf16* __restrict__ Wc,
    float* __restrict__ bc, unsigned int* __restrict__ ctr,
    float* __restrict__ out) {
  __shared__ char lds[73728];  // 72 KB -> 2 blocks/CU (144/160 KB)

  const int t = threadIdx.x;
  const int w = t >> 6, l = t & 63;
  const int b = blockIdx.x;
  const int C0 = (b & 1) * 128;  // column half

  const float* __restrict__ Wv = Wqkv + 2 * DD * DD;
  const float* __restrict__ bv = bqkv + 2 * DD;

  // ================= Phase 1: Wc row i, cols [C0, C0+128) =================
  {
    float* wvbuf = (float*)lds;             // 32 KB chunk buffer
    float* wout_s = (float*)(lds + 32768);  // 1 KB
    float* part = (float*)(lds + 33792);    // 2 KB (4 x 128)
    const int i = b >> 1;

    if (t < 64)
      *(f32x4*)(wout_s + t * 4) = *(const f32x4*)(Wout + (size_t)i * DD + t * 4);

    const int j128 = t & 127, dgrp = t >> 7;
    float acc = 0.f;
    for (int c = 0; c < 4; ++c) {  // 4 chunks of 64 Wv rows x 128 cols
#pragma unroll
      for (int j = 0; j < 4; ++j) {
        const int L = (w * 4 + j) * 1024 + l * 16;
        const int grow = L >> 9, gbyte = L & 511;
        gl2lds16((const char*)Wv + (size_t)(c * 64 + grow) * 1024 + C0 * 4 + gbyte,
                 (char*)wvbuf + w * 4096 + j * 1024);
      }
      __syncthreads();  // drain DMA (and publish wout_s on c==0)
#pragma unroll
      for (int k = 0; k < 16; ++k) {
        const int dd = dgrp * 16 + k;
        acc += wout_s[c * 64 + dd] * wvbuf[dd * 128 + j128];
      }
      __syncthreads();  // buffer reuse
    }
    part[dgrp * 128 + j128] = acc;
    __syncthreads();
    if (t < 64) {
      const float s0 = part[2 * t] + part[128 + 2 * t] + part[256 + 2 * t] + part[384 + 2 * t];
      const float s1 = part[2 * t + 1] + part[128 + 2 * t + 1] + part[256 + 2 * t + 1] + part[384 + 2 * t + 1];
      const unsigned short u0 = __builtin_bit_cast(unsigned short, (__bf16)s0);
      const unsigned short u1 = __builtin_bit_cast(unsigned short, (__bf16)s1);
      // device-scope RMW write -> lands at coherence point (cross-XCD safe)
      atomicExch((unsigned int*)((char*)Wc + ((size_t)i * DD + C0 + 2 * t) * 2),
                 (unsigned int)u0 | ((unsigned int)u1 << 16));
      if (C0 == 0) {  // bc[i]
        float p = 0.f;
#pragma unroll
        for (int k = 0; k < 4; ++k) p += wout_s[t + 64 * k] * bv[t + 64 * k];
#pragma unroll
        for (int off = 32; off > 0; off >>= 1) p += __shfl_down(p, off);
        if (t == 0) atomicExch((unsigned int*)(bc + i),
                               __builtin_bit_cast(unsigned int, bout[i] + p));
      }
    }
    __syncthreads();  // all phase-1 atomics issued; barrier waits vmcnt(0)
  }

  // ================= Grid barrier (all 512 blocks resident) ===============
  __threadfence();  // release
  if (t == 0) {
    atomicAdd(ctr, 1u);
    while (atomicAdd(ctr, 0u) < NBLK) __builtin_amdgcn_s_sleep(32);
  }
  __syncthreads();
  __threadfence();  // acquire: invalidate caches before reading Wc/bc

  // ================= Phase 2: out = x + x @ Wc^T + bc =====================
  __bf16* wc_s = (__bf16*)lds;           // 64 KB: Wc rows [C0,+128), swizzled
  __bf16* xs = (__bf16*)(lds + 65536);   // 8 KB: 16 x-rows bf16, swizzled
  const int rowblk = (b >> 1) * 64;

  // DMA Wc slice with pre-swizzled source (linear dest + swz read; R7-passed)
#pragma unroll
  for (int j = 0; j < 8; ++j) {
    const int L = (w * 8 + j) * 1024 + l * 16;
    const int row = L >> 9;
    const int srow = (L & 511) ^ ((row & 7) << 4);
    gl2lds16((const char*)Wc + (size_t)(C0 + row) * 512 + srow,
             (char*)wc_s + w * 8192 + j * 1024);
  }

  const int rA = w * 16 + (l & 15);  // wc_s row (out-col local)
  const int csw = (rA & 7) << 4;
  const int xrow = l & 15;
  const int xsw = (xrow & 7) << 4;
  const int g4 = l >> 4;

  for (int rt = 0; rt < 4; ++rt) {
    const int R0 = rowblk + rt * 16;
    // stage x tile: thread -> row t>>5, 8 floats at (t&31)*8 (issued early)
    const float* src = x + (size_t)(R0 + (t >> 5)) * DD + (t & 31) * 8;
    f32x4 lo = *(const f32x4*)(src);
    f32x4 hi = *(const f32x4*)(src + 4);
    bf16x8 v = cvt8(lo, hi);
    __syncthreads();  // rt==0: drains wc_s DMA; else: xs readers done
    {
      const int r = t >> 5;
      *(bf16x8*)((char*)xs + (((r * 512) + (t & 31) * 16) ^ ((r & 7) << 4))) = v;
    }
    __syncthreads();

    f32x4 acc = {0.f, 0.f, 0.f, 0.f};
#pragma unroll
    for (int ks = 0; ks < 8; ++ks) {
      const int kb = ks * 64 + g4 * 16;
      bf16x8 af = *(const bf16x8*)((const char*)wc_s + ((rA * 512 + kb) ^ csw));
      bf16x8 bfr = *(const bf16x8*)((const char*)xs + ((xrow * 512 + kb) ^ xsw));
      acc = __builtin_amdgcn_mfma_f32_16x16x32_bf16(af, bfr, acc, 0, 0, 0);
    }
    // D: col(l&15)=x-row, rowquad g4*4+reg = out-col offset (R7-verified)
    const int ocol = C0 + w * 16 + g4 * 4;
    const size_t idx = (size_t)(R0 + xrow) * DD + ocol;
    f32x4 xres = *(const f32x4*)(x + idx);   // exact fp32 residual
    f32x4 bias = *(const f32x4*)(bc + ocol); // includes bout
    *(f32x4*)(out + idx) = acc + xres + bias;
  }
}

extern "C" void kernel_launch(void* const* d_in, const int* in_sizes, int n_in,
                              void* d_out, int out_size, void* d_ws, size_t ws_size,
                              hipStream_t stream) {
  const float* x = (const float*)d_in[0];
  const float* Wqkv = (const float*)d_in[1];
  const float* bqkv = (const float*)d_in[2];
  const float* Wout = (const float*)d_in[3];
  const float* bout = (const float*)d_in[4];
  float* out = (float*)d_out;

  __bf16* Wc = (__bf16*)d_ws;                                    // 128 KiB
  float* bc = (float*)((char*)d_ws + DD * DD * sizeof(__bf16));  // +1 KiB
  unsigned int* ctr = (unsigned int*)((char*)d_ws + 132 * 1024); // barrier ctr

  // Zero the barrier counter every replay (memset node is graph-capturable).
  hipMemsetAsync(ctr, 0, sizeof(unsigned int), stream);
  fused_knn<<<NBLK, 512, 0, stream>>>(x, Wqkv, bqkv, Wout, bout, Wc, bc, ctr, out);
}